// Round 1
// baseline (89.126 us; speedup 1.0000x reference)
//
#include <hip/hip_runtime.h>

namespace {
constexpr int kB = 1024;
constexpr int kN = 40;
constexpr int kE = 64;
constexpr int kP = kN * (kN - 1) / 2;  // 780

using bf16x8 = __attribute__((ext_vector_type(8))) short;
using f32x4  = __attribute__((ext_vector_type(4))) float;
using f32x2  = __attribute__((ext_vector_type(2))) float;

__device__ inline unsigned short f2bf(float x) {  // RNE fp32->bf16
  union { float f; unsigned u; } v; v.f = x;
  return (unsigned short)((v.u + 0x7FFFu + ((v.u >> 16) & 1u)) >> 16);
}

// ---- fused prep (R6-proven, unchanged) ----
// blocks [0, 640): x (B,N,E) fp32 -> B-frag layout xf:
//   per (n,bg): 1024 shorts [ks:2][lane:64][j:8] = x[bg*16+(L&15)][n][ks*32+(L>>4)*8+j]
// blocks [640, 1420): param -> A-frag layout Af: per pair i: 4096 shorts,
//   chunk (mt*2+ks)*512 + L*8 holds M_i[16mt+(L&15)][ks*32+(L>>4)*8+j]
__global__ __launch_bounds__(256) void prep(const float* __restrict__ in,
                                            const float* __restrict__ param,
                                            unsigned short* __restrict__ xf,
                                            unsigned short* __restrict__ Af) {
  __shared__ short Ms[64 * 72];
  const int t = threadIdx.x;
  if (blockIdx.x < 640) {
    const int n    = blockIdx.x >> 4;
    const int bgc  = blockIdx.x & 15;
    const int bgl  = t >> 6;
    const int L    = t & 63;
    const int col  = L & 15;
    const int quad = L >> 4;
    const int b    = (bgc * 4 + bgl) * 16 + col;
    const float* src    = in + ((size_t)b * kN + n) * kE + quad * 8;
    unsigned short* dst = xf + (((size_t)n * 64 + bgc * 4 + bgl) << 10) + L * 8;
    const float4 v0 = ((const float4*)src)[0];
    const float4 v1 = ((const float4*)src)[1];
    const float4 v2 = ((const float4*)(src + 32))[0];
    const float4 v3 = ((const float4*)(src + 32))[1];
    bf16x8 o0, o1;
    o0[0] = (short)f2bf(v0.x); o0[1] = (short)f2bf(v0.y);
    o0[2] = (short)f2bf(v0.z); o0[3] = (short)f2bf(v0.w);
    o0[4] = (short)f2bf(v1.x); o0[5] = (short)f2bf(v1.y);
    o0[6] = (short)f2bf(v1.z); o0[7] = (short)f2bf(v1.w);
    o1[0] = (short)f2bf(v2.x); o1[1] = (short)f2bf(v2.y);
    o1[2] = (short)f2bf(v2.z); o1[3] = (short)f2bf(v2.w);
    o1[4] = (short)f2bf(v3.x); o1[5] = (short)f2bf(v3.y);
    o1[6] = (short)f2bf(v3.z); o1[7] = (short)f2bf(v3.w);
    *(bf16x8*)dst         = o0;
    *(bf16x8*)(dst + 512) = o1;
  } else {
    const int i = blockIdx.x - 640;  // pair index
#pragma unroll
    for (int ph = 0; ph < 4; ++ph) {
      const int f  = ph * 16 + (t >> 4);
      const int e0 = (t & 15) * 4;
      const float4 v = *(const float4*)(param + ((size_t)f * kP + i) * kE + e0);
      short* d = &Ms[f * 72 + e0];
      d[0] = (short)f2bf(v.x); d[1] = (short)f2bf(v.y);
      d[2] = (short)f2bf(v.z); d[3] = (short)f2bf(v.w);
    }
    __syncthreads();
    unsigned short* base = Af + (size_t)i * 4096;
#pragma unroll
    for (int u = 0; u < 2; ++u) {
      const int chunk = t * 2 + u;       // 0..511
      const int L    = chunk & 63;
      const int mtks = chunk >> 6;
      const int mt   = mtks >> 1, ks = mtks & 1;
      const int col  = L & 15, quad = L >> 4;
      const bf16x8 a = *(const bf16x8*)&Ms[(16 * mt + col) * 72 + ks * 32 + quad * 8];
      *(bf16x8*)(base + chunk * 8) = a;
    }
  }
}

// ---- main (R6 pair2 structure; ring reduced 3->2 slots for VGPR relief) ----
// block = (r, c0..c0+1) x 256 batches; 4 waves = 2 cc x 2 batch-halves, 8 bgs/wave.
// 2-slot ring: core live state = A(32) + B(16) + Qv(16) + acc(16) = 80 VGPR,
// comfortably under the __launch_bounds__(256,4) 128-VGPR cap (3-slot ring was
// ~120-135 demanded -> spill risk at the cap).
__global__ __launch_bounds__(256, 4)
void opn_pair3(const unsigned short* __restrict__ xf,
               const unsigned short* __restrict__ Af,
               float* __restrict__ out) {  // (B,1,P) fp32
  __shared__ float dots[256 * 2];  // [b_local][cc]

  const int t    = threadIdx.x;
  const int w    = t >> 6;
  const int L    = t & 63;
  const int col  = L & 15;
  const int quad = L >> 4;

  // decode blockIdx.x -> (r, c0): rows r=0..38, (40-r)>>1 c-pair tiles each (400 total)
  int tx = blockIdx.x, r = 0;
  for (;;) { const int nq = (40 - r) >> 1; if (tx < nq) break; tx -= nq; ++r; }
  const int c0  = r + 1 + tx * 2;
  const int ib  = r * (79 - r) / 2 + c0 - r - 1;  // pair index of (r, c0)
  const int gb0 = blockIdx.y * 256;

  const int cc = w & 1;
  const int h  = w >> 1;
  const int c  = c0 + cc;

  if (c <= kN - 1) {
    // A-frags: 8 dense 16B loads (HW-verified mapping)
    const unsigned short* ab = Af + (size_t)(ib + cc) * 4096 + L * 8;
    bf16x8 A[4][2];
#pragma unroll
    for (int mt = 0; mt < 4; ++mt)
#pragma unroll
      for (int ks = 0; ks < 2; ++ks)
        A[mt][ks] = *(const bf16x8*)(ab + (mt * 2 + ks) * 512);

    const int bgg0 = blockIdx.y * 16 + h * 8;
    const unsigned short* pb = xf + (((size_t)r * 64 + bgg0) << 10);
    const unsigned short* qb = xf + (((size_t)c * 64 + bgg0) << 10);
    const int qoff = (quad >> 1) * 128 + col * 8 + (quad & 1) * 4;  // 8B-aligned

    // 2-slot ring: prefetch depth 1
    bf16x8 B0[2], B1[2];
    uint2  Qv[2][4];
    {
      B0[0]    = *(const bf16x8*)(pb + L * 8);
      B1[0]    = *(const bf16x8*)(pb + 512 + L * 8);
      Qv[0][0] = *(const uint2*)(qb + qoff);
      Qv[0][1] = *(const uint2*)(qb + 256 + qoff);
      Qv[0][2] = *(const uint2*)(qb + 512 + qoff);
      Qv[0][3] = *(const uint2*)(qb + 768 + qoff);
    }

#pragma unroll
    for (int bg = 0; bg < 8; ++bg) {
      const int s = bg & 1;
      if (bg < 7) {
        const int ps = s ^ 1;
        const unsigned short* pn = pb + ((size_t)(bg + 1) << 10);
        const unsigned short* qn = qb + ((size_t)(bg + 1) << 10);
        B0[ps]    = *(const bf16x8*)(pn + L * 8);
        B1[ps]    = *(const bf16x8*)(pn + 512 + L * 8);
        Qv[ps][0] = *(const uint2*)(qn + qoff);
        Qv[ps][1] = *(const uint2*)(qn + 256 + qoff);
        Qv[ps][2] = *(const uint2*)(qn + 512 + qoff);
        Qv[ps][3] = *(const uint2*)(qn + 768 + qoff);
      }
      f32x4 acc[4];
#pragma unroll
      for (int mt = 0; mt < 4; ++mt) acc[mt] = (f32x4){0.f, 0.f, 0.f, 0.f};
#pragma unroll
      for (int mt = 0; mt < 4; ++mt) {
        acc[mt] = __builtin_amdgcn_mfma_f32_16x16x32_bf16(A[mt][0], B0[s], acc[mt], 0, 0, 0);
        acc[mt] = __builtin_amdgcn_mfma_f32_16x16x32_bf16(A[mt][1], B1[s], acc[mt], 0, 0, 0);
      }
      // packed epilogue: q bf16 pairs -> f32x2 via bit-ops, pk-fma accumulate
      f32x2 d2 = (f32x2){0.f, 0.f};
#pragma unroll
      for (int mt = 0; mt < 4; ++mt) {
        const uint2 u = Qv[s][mt];
        const f32x2 qlo = (f32x2){__uint_as_float(u.x << 16),
                                  __uint_as_float(u.x & 0xFFFF0000u)};
        const f32x2 qhi = (f32x2){__uint_as_float(u.y << 16),
                                  __uint_as_float(u.y & 0xFFFF0000u)};
        const f32x2 a01 = (f32x2){acc[mt][0], acc[mt][1]};
        const f32x2 a23 = (f32x2){acc[mt][2], acc[mt][3]};
        d2 = a01 * qlo + d2;  // v_pk_fma_f32
        d2 = a23 * qhi + d2;
      }
      float dot = d2[0] + d2[1];
      dot += __shfl_xor(dot, 16, 64);
      dot += __shfl_xor(dot, 32, 64);
      if (quad == 0) dots[(h * 128 + bg * 16 + col) * 2 + cc] = dot;
    }
  }
  __syncthreads();

  // out-phase: thread t -> batch t; 8B run per b
  const float2 dv = *(const float2*)&dots[t * 2];
  float* ob = out + (size_t)(gb0 + t) * kP + ib;
  ob[0] = dv.x;
  if (c0 + 1 <= kN - 1) ob[1] = dv.y;
}

// ---- fallback (no ws): fp32 path ----
__global__ __launch_bounds__(256, 2)
void opn_fp32(const float* __restrict__ inp, const float* __restrict__ param,
              float* __restrict__ out) {
  const int i    = blockIdx.x;
  const int wave = threadIdx.x >> 6;
  const int lane = threadIdx.x & 63;
  const int b    = (blockIdx.y * 4 + wave) * 64 + lane;
  int rem = i, r = 0;
  while (rem >= kN - 1 - r) { rem -= kN - 1 - r; ++r; }
  const int c = r + 1 + rem;
  const float* pb = inp + (size_t)b * (kN * kE) + r * kE;
  const float* qb = inp + (size_t)b * (kN * kE) + c * kE;
  float p[kE];
#pragma unroll
  for (int e = 0; e < kE; ++e) p[e] = pb[e];
  float acc = 0.f;
  for (int f = 0; f < kE; ++f) {
    const float* Mrow = param + ((size_t)f * kP + i) * kE;
    float t0 = 0.f, t1 = 0.f, t2 = 0.f, t3 = 0.f;
#pragma unroll
    for (int e = 0; e < kE; e += 4) {
      t0 = fmaf(Mrow[e + 0], p[e + 0], t0);
      t1 = fmaf(Mrow[e + 1], p[e + 1], t1);
      t2 = fmaf(Mrow[e + 2], p[e + 2], t2);
      t3 = fmaf(Mrow[e + 3], p[e + 3], t3);
    }
    acc = fmaf((t0 + t1) + (t2 + t3), qb[f], acc);
  }
  out[(size_t)b * kP + i] = acc;
}
}  // namespace

extern "C" void kernel_launch(void* const* d_in, const int* in_sizes, int n_in,
                              void* d_out, int out_size, void* d_ws, size_t ws_size,
                              hipStream_t stream) {
  const float* inputs = (const float*)d_in[0];  // (B, N, E) fp32
  const float* param  = (const float*)d_in[1];  // (E, P, E) fp32
  float* out          = (float*)d_out;          // (B, 1, P) fp32

  const size_t xf_bytes = (size_t)kN * kB * kE * sizeof(unsigned short);   // 5.24 MB
  const size_t af_bytes = (size_t)kP * 4096 * sizeof(unsigned short);      // 6.39 MB

  if (ws_size >= xf_bytes + af_bytes) {
    unsigned short* xf = (unsigned short*)d_ws;
    unsigned short* Af = (unsigned short*)((char*)d_ws + xf_bytes);
    prep<<<640 + kP, 256, 0, stream>>>(inputs, param, xf, Af);
    opn_pair3<<<dim3(400, 4), 256, 0, stream>>>(xf, Af, out);
  } else {
    opn_fp32<<<dim3(kP, 4), 256, 0, stream>>>(inputs, param, out);
  }
}